// Round 1
// baseline (881.985 us; speedup 1.0000x reference)
//
#include <hip/hip_runtime.h>
#include <hip/hip_bf16.h>

#define T_TOK 1024
#define H_DIM 2048
#define I_DIM 1024
#define NE 32

typedef __attribute__((ext_vector_type(8))) short bf16x8_t;
typedef __attribute__((ext_vector_type(4))) float f32x4_t;

__device__ __forceinline__ unsigned short f2bf(float f) {
    unsigned int u = __builtin_bit_cast(unsigned int, f);
    u += 0x7fffu + ((u >> 16) & 1u);   // RNE
    return (unsigned short)(u >> 16);
}

__device__ __forceinline__ ushort4 f42bf(float4 v) {
    ushort4 r; r.x = f2bf(v.x); r.y = f2bf(v.y); r.z = f2bf(v.z); r.w = f2bf(v.w);
    return r;
}

// ---------------- Router: logits -> top-2 -> renorm -> bucket per expert ----------------
__global__ __launch_bounds__(256) void moe_router(
    const float* __restrict__ x, const float* __restrict__ gwr,
    int* __restrict__ counts, int* __restrict__ etok, float* __restrict__ ew)
{
    const int t = blockIdx.x;
    const int e = threadIdx.x >> 3;   // 32 experts x 8 threads
    const int j = threadIdx.x & 7;
    const float* xr = x + (size_t)t * H_DIM;
    const float* wr = gwr + (size_t)e * H_DIM;
    double s = 0.0;                   // fp64 accum: avoid top-2 flips vs reference
    for (int c = j * 4; c < H_DIM; c += 32) {
        float4 a = *(const float4*)(xr + c);
        float4 b = *(const float4*)(wr + c);
        s += (double)a.x * b.x + (double)a.y * b.y + (double)a.z * b.z + (double)a.w * b.w;
    }
    s += __shfl_down(s, 4, 8);
    s += __shfl_down(s, 2, 8);
    s += __shfl_down(s, 1, 8);
    __shared__ float lg[NE];
    if (j == 0) lg[e] = (float)s;
    __syncthreads();
    if (threadIdx.x == 0) {
        float l1 = -1e30f, l2 = -1e30f; int i1 = 0, i2 = 0;
        for (int k = 0; k < NE; k++) {
            float v = lg[k];
            if (v > l1) { l2 = l1; i2 = i1; l1 = v; i1 = k; }
            else if (v > l2) { l2 = v; i2 = k; }
        }
        // renormalized top-2 softmax weights: p1/(p1+p2) = 1/(1+exp(l2-l1))
        float w2 = 1.f / (1.f + __expf(l1 - l2));
        float w1 = 1.f - w2;
        int p1 = atomicAdd(&counts[i1], 1);
        etok[i1 * T_TOK + p1] = (t << 1);
        ew[i1 * T_TOK + p1] = w1;
        int p2 = atomicAdd(&counts[i2], 1);
        etok[i2 * T_TOK + p2] = (t << 1) | 1;
        ew[i2 * T_TOK + p2] = w2;
    }
}

// ---------------- Gate+Up grouped GEMM: h = silu(x@Wg^T) * (x@Wu^T) * w ----------------
// grid (8 I-tiles, 32 experts), 512 threads = 8 waves, M-tile 128, N = 128 gate + 128 up
__global__ __launch_bounds__(512, 2) void moe_gateup(
    const float* __restrict__ x,
    const float* __restrict__ gw,   // [E, I, H]
    const float* __restrict__ uw,   // [E, I, H]
    const int* __restrict__ counts,
    const int* __restrict__ etok,
    const float* __restrict__ ew,
    unsigned short* __restrict__ hbuf)  // [2T, I] bf16
{
    __shared__ __align__(16) unsigned char smem[67584];
    unsigned short* As = (unsigned short*)smem;            // [128][72] bf16
    unsigned short* Gs = (unsigned short*)(smem + 18432);  // [128][72]
    unsigned short* Us = (unsigned short*)(smem + 36864);  // [128][72]
    float* GL = (float*)smem;                              // epilogue gate C [128][132]

    const int e   = blockIdx.y;
    const int i0  = blockIdx.x * 128;
    const int cnt = counts[e];
    const int tid = threadIdx.x;
    const int wid = tid >> 6, lane = tid & 63;
    const int wm = wid >> 2, wn = wid & 3;       // wave grid 2 (M) x 4 (N)
    const int lrow = lane & 15, quad = lane >> 4;

    const unsigned short* Bsrc = (wn < 2) ? Gs : Us;
    const int bro = (wn & 1) * 64;

    for (int m0 = 0; m0 < cnt; m0 += 128) {
        f32x4_t acc[4][4];
        #pragma unroll
        for (int a = 0; a < 4; a++)
            #pragma unroll
            for (int b = 0; b < 4; b++) acc[a][b] = (f32x4_t){0.f, 0.f, 0.f, 0.f};

        for (int k0 = 0; k0 < H_DIM; k0 += 64) {
            __syncthreads();
            #pragma unroll
            for (int i = 0; i < 4; i++) {        // A tile: gathered x rows, fp32->bf16
                int idx = tid + i * 512;
                int row = idx >> 4, c4 = idx & 15;
                int m = m0 + row;
                int tok = (m < cnt) ? (etok[e * T_TOK + m] >> 1) : 0;
                float4 v = *(const float4*)(x + (size_t)tok * H_DIM + k0 + c4 * 4);
                *(ushort4*)(As + row * 72 + c4 * 4) = f42bf(v);
            }
            #pragma unroll
            for (int i = 0; i < 4; i++) {        // gate weights
                int idx = tid + i * 512;
                int row = idx >> 4, c4 = idx & 15;
                float4 v = *(const float4*)(gw + ((size_t)e * I_DIM + i0 + row) * H_DIM + k0 + c4 * 4);
                *(ushort4*)(Gs + row * 72 + c4 * 4) = f42bf(v);
            }
            #pragma unroll
            for (int i = 0; i < 4; i++) {        // up weights
                int idx = tid + i * 512;
                int row = idx >> 4, c4 = idx & 15;
                float4 v = *(const float4*)(uw + ((size_t)e * I_DIM + i0 + row) * H_DIM + k0 + c4 * 4);
                *(ushort4*)(Us + row * 72 + c4 * 4) = f42bf(v);
            }
            __syncthreads();
            #pragma unroll
            for (int kk = 0; kk < 2; kk++) {
                bf16x8_t af[4], bfr[4];
                #pragma unroll
                for (int q = 0; q < 4; q++)
                    af[q] = *(const bf16x8_t*)(As + (wm * 64 + q * 16 + lrow) * 72 + kk * 32 + quad * 8);
                #pragma unroll
                for (int q = 0; q < 4; q++)
                    bfr[q] = *(const bf16x8_t*)(Bsrc + (bro + q * 16 + lrow) * 72 + kk * 32 + quad * 8);
                #pragma unroll
                for (int a = 0; a < 4; a++)
                    #pragma unroll
                    for (int b = 0; b < 4; b++)
                        acc[a][b] = __builtin_amdgcn_mfma_f32_16x16x32_bf16(af[a], bfr[b], acc[a][b], 0, 0, 0);
            }
        }
        // epilogue: gate waves -> LDS, up waves combine silu(g)*u*w -> hbuf (bf16)
        __syncthreads();
        if (wn < 2) {
            #pragma unroll
            for (int a = 0; a < 4; a++)
                #pragma unroll
                for (int b = 0; b < 4; b++)
                    #pragma unroll
                    for (int r = 0; r < 4; r++) {
                        int row = wm * 64 + a * 16 + quad * 4 + r;
                        int col = wn * 64 + b * 16 + lrow;
                        GL[row * 132 + col] = acc[a][b][r];
                    }
        }
        __syncthreads();
        if (wn >= 2) {
            #pragma unroll
            for (int a = 0; a < 4; a++)
                #pragma unroll
                for (int r = 0; r < 4; r++) {
                    int row = wm * 64 + a * 16 + quad * 4 + r;
                    int m = m0 + row;
                    if (m < cnt) {
                        int ent = etok[e * T_TOK + m];
                        float w = ew[e * T_TOK + m];
                        #pragma unroll
                        for (int b = 0; b < 4; b++) {
                            int colI = (wn - 2) * 64 + b * 16 + lrow;
                            float g = GL[row * 132 + colI];
                            float u = acc[a][b][r];
                            float hv = g / (1.f + __expf(-g)) * u * w;
                            hbuf[(size_t)ent * I_DIM + i0 + colI] = f2bf(hv);
                        }
                    }
                }
        }
    }
}

// ---------------- Down grouped GEMM: out[tok] += h @ Wd^T (scatter atomicAdd) ----------------
// grid (8 H-tiles, 32 experts), 512 threads, M-tile 128, N-tile 256, K = I
__global__ __launch_bounds__(512, 2) void moe_down(
    const unsigned short* __restrict__ hbuf,  // [2T, I] bf16
    const float* __restrict__ dw,             // [E, H, I]
    const int* __restrict__ counts,
    const int* __restrict__ etok,
    float* __restrict__ out)                  // [T, H] fp32, pre-zeroed
{
    __shared__ __align__(16) unsigned char smem[55296];
    unsigned short* As = (unsigned short*)smem;            // [128][72]
    unsigned short* Ds = (unsigned short*)(smem + 18432);  // [256][72]

    const int e   = blockIdx.y;
    const int n0  = blockIdx.x * 256;
    const int cnt = counts[e];
    const int tid = threadIdx.x;
    const int wid = tid >> 6, lane = tid & 63;
    const int wm = wid >> 2, wn = wid & 3;
    const int lrow = lane & 15, quad = lane >> 4;

    for (int m0 = 0; m0 < cnt; m0 += 128) {
        f32x4_t acc[4][4];
        #pragma unroll
        for (int a = 0; a < 4; a++)
            #pragma unroll
            for (int b = 0; b < 4; b++) acc[a][b] = (f32x4_t){0.f, 0.f, 0.f, 0.f};

        for (int k0 = 0; k0 < I_DIM; k0 += 64) {
            __syncthreads();
            #pragma unroll
            for (int i = 0; i < 2; i++) {        // A: gathered bf16 h rows (no convert)
                int idx = tid + i * 512;         // 1024 chunks of 16B
                int row = idx >> 3, c8 = idx & 7;
                int m = m0 + row;
                int ent = (m < cnt) ? etok[e * T_TOK + m] : 0;
                uint4 v = *(const uint4*)(hbuf + (size_t)ent * I_DIM + k0 + c8 * 8);
                *(uint4*)(As + row * 72 + c8 * 8) = v;
            }
            #pragma unroll
            for (int i = 0; i < 8; i++) {        // down weights fp32->bf16
                int idx = tid + i * 512;         // 4096 float4 chunks
                int row = idx >> 4, c4 = idx & 15;
                float4 v = *(const float4*)(dw + ((size_t)e * H_DIM + n0 + row) * I_DIM + k0 + c4 * 4);
                *(ushort4*)(Ds + row * 72 + c4 * 4) = f42bf(v);
            }
            __syncthreads();
            #pragma unroll
            for (int kk = 0; kk < 2; kk++) {
                bf16x8_t af[4], bfr[4];
                #pragma unroll
                for (int q = 0; q < 4; q++)
                    af[q] = *(const bf16x8_t*)(As + (wm * 64 + q * 16 + lrow) * 72 + kk * 32 + quad * 8);
                #pragma unroll
                for (int q = 0; q < 4; q++)
                    bfr[q] = *(const bf16x8_t*)(Ds + (wn * 64 + q * 16 + lrow) * 72 + kk * 32 + quad * 8);
                #pragma unroll
                for (int a = 0; a < 4; a++)
                    #pragma unroll
                    for (int b = 0; b < 4; b++)
                        acc[a][b] = __builtin_amdgcn_mfma_f32_16x16x32_bf16(af[a], bfr[b], acc[a][b], 0, 0, 0);
            }
        }
        #pragma unroll
        for (int a = 0; a < 4; a++)
            #pragma unroll
            for (int r = 0; r < 4; r++) {
                int row = wm * 64 + a * 16 + quad * 4 + r;
                int m = m0 + row;
                if (m < cnt) {
                    int tok = etok[e * T_TOK + m] >> 1;
                    float* orow = out + (size_t)tok * H_DIM + n0 + wn * 64;
                    #pragma unroll
                    for (int b = 0; b < 4; b++)
                        atomicAdd(orow + b * 16 + lrow, acc[a][b][r]);
                }
            }
    }
}

extern "C" void kernel_launch(void* const* d_in, const int* in_sizes, int n_in,
                              void* d_out, int out_size, void* d_ws, size_t ws_size,
                              hipStream_t stream) {
    const float* x   = (const float*)d_in[0];   // [T, H]
    const float* gwr = (const float*)d_in[1];   // [E, H] router
    const float* gw  = (const float*)d_in[2];   // [E, I, H]
    const float* uw  = (const float*)d_in[3];   // [E, I, H]
    const float* dw  = (const float*)d_in[4];   // [E, H, I]
    float* out = (float*)d_out;

    char* ws = (char*)d_ws;
    int*   counts = (int*)ws;                                // 32 ints (zeroed below)
    int*   etok   = (int*)(ws + 4096);                       // [E*T] (token<<1 | slot)
    float* ew     = (float*)(ws + 4096 + 131072);            // [E*T] combine weight
    unsigned short* hbuf = (unsigned short*)(ws + 4096 + 262144);  // [2T, I] bf16 = 4 MB
    // total ws use: ~4.46 MB

    hipMemsetAsync(counts, 0, 128, stream);
    hipMemsetAsync(d_out, 0, (size_t)out_size * sizeof(float), stream);

    moe_router<<<T_TOK, 256, 0, stream>>>(x, gwr, counts, etok, ew);
    moe_gateup<<<dim3(I_DIM / 128, NE), 512, 0, stream>>>(x, gw, uw, counts, etok, ew, hbuf);
    moe_down<<<dim3(H_DIM / 256, NE), 512, 0, stream>>>(hbuf, dw, counts, etok, out);
}

// Round 2
// 827.969 us; speedup vs baseline: 1.0652x; 1.0652x over previous
//
#include <hip/hip_runtime.h>
#include <hip/hip_bf16.h>

#define T_TOK 1024
#define H_DIM 2048
#define I_DIM 1024
#define NE 32

typedef __attribute__((ext_vector_type(8))) short bf16x8_t;
typedef __attribute__((ext_vector_type(4))) float f32x4_t;

__device__ __forceinline__ unsigned short f2bf(float f) {
    unsigned int u = __builtin_bit_cast(unsigned int, f);
    u += 0x7fffu + ((u >> 16) & 1u);   // RNE
    return (unsigned short)(u >> 16);
}

__device__ __forceinline__ ushort4 f42bf(float4 v) {
    ushort4 r; r.x = f2bf(v.x); r.y = f2bf(v.y); r.z = f2bf(v.z); r.w = f2bf(v.w);
    return r;
}

// ---------------- Router: logits -> top-2 -> renorm -> bucket per expert ----------------
__global__ __launch_bounds__(256) void moe_router(
    const float* __restrict__ x, const float* __restrict__ gwr,
    int* __restrict__ counts, int* __restrict__ etok, float* __restrict__ ew)
{
    const int t = blockIdx.x;
    const int e = threadIdx.x >> 3;   // 32 experts x 8 threads
    const int j = threadIdx.x & 7;
    const float* xr = x + (size_t)t * H_DIM;
    const float* wr = gwr + (size_t)e * H_DIM;
    double s = 0.0;                   // fp64 accum: avoid top-2 flips vs reference
    for (int c = j * 4; c < H_DIM; c += 32) {
        float4 a = *(const float4*)(xr + c);
        float4 b = *(const float4*)(wr + c);
        s += (double)a.x * b.x + (double)a.y * b.y + (double)a.z * b.z + (double)a.w * b.w;
    }
    s += __shfl_down(s, 4, 8);
    s += __shfl_down(s, 2, 8);
    s += __shfl_down(s, 1, 8);
    __shared__ float lg[NE];
    if (j == 0) lg[e] = (float)s;
    __syncthreads();
    if (threadIdx.x == 0) {
        float l1 = -1e30f, l2 = -1e30f; int i1 = 0, i2 = 0;
        for (int k = 0; k < NE; k++) {
            float v = lg[k];
            if (v > l1) { l2 = l1; i2 = i1; l1 = v; i1 = k; }
            else if (v > l2) { l2 = v; i2 = k; }
        }
        float w2 = 1.f / (1.f + __expf(l1 - l2));
        float w1 = 1.f - w2;
        int p1 = atomicAdd(&counts[i1], 1);
        etok[i1 * T_TOK + p1] = (t << 1);
        ew[i1 * T_TOK + p1] = w1;
        int p2 = atomicAdd(&counts[i2], 1);
        etok[i2 * T_TOK + p2] = (t << 1) | 1;
        ew[i2 * T_TOK + p2] = w2;
    }
}

// ---------------- Gate+Up grouped GEMM: h = silu(x@Wg^T) * (x@Wu^T) * w ----------------
// grid (16 I-tiles of 64, 32 experts) = 512 blocks, 512 thr, M=128, N=64g+64u, BK=64
// double-buffered LDS + register prefetch: one barrier per K-step
__global__ __launch_bounds__(512, 4) void moe_gateup(
    const float* __restrict__ x,
    const float* __restrict__ gw,   // [E, I, H]
    const float* __restrict__ uw,   // [E, I, H]
    const int* __restrict__ counts,
    const int* __restrict__ etok,
    const float* __restrict__ ew,
    unsigned short* __restrict__ hbuf)  // [2T, I] bf16
{
    // per buffer (36864 B): A[128][72] bf16 (18432) | G[64][72] (9216) | U[64][72] (9216)
    __shared__ __align__(16) unsigned char smem[73728];
    const int e   = blockIdx.y;
    const int i0  = blockIdx.x * 64;
    const int cnt = counts[e];
    const int tid = threadIdx.x;
    const int wid = tid >> 6, lane = tid & 63;
    const int wm = wid >> 1, wn = wid & 1;      // 4 M-waves x 2 N-waves (gate/up)
    const int lrow = lane & 15, quad = lane >> 4;

    const float* gbase = gw + ((size_t)e * I_DIM + i0 + (tid >> 4)) * H_DIM + (tid & 15) * 4;
    const float* ubase = uw + ((size_t)e * I_DIM + i0 + (tid >> 4)) * H_DIM + (tid & 15) * 4;

    for (int m0 = 0; m0 < cnt; m0 += 128) {
        const float* arow[4];
        #pragma unroll
        for (int i = 0; i < 4; i++) {
            int idx = tid + i * 512;
            int m = m0 + (idx >> 4);
            int tok = (m < cnt) ? (etok[e * T_TOK + m] >> 1) : 0;
            arow[i] = x + (size_t)tok * H_DIM + (idx & 15) * 4;
        }

        f32x4_t acc[2][4];
        #pragma unroll
        for (int a = 0; a < 2; a++)
            #pragma unroll
            for (int c = 0; c < 4; c++) acc[a][c] = (f32x4_t){0.f, 0.f, 0.f, 0.f};

        float4 ra[4], rg[2], ru[2];
        auto load_t = [&](int k0) {
            #pragma unroll
            for (int i = 0; i < 4; i++) ra[i] = *(const float4*)(arow[i] + k0);
            #pragma unroll
            for (int i = 0; i < 2; i++) rg[i] = *(const float4*)(gbase + (size_t)i * 32 * H_DIM + k0);
            #pragma unroll
            for (int i = 0; i < 2; i++) ru[i] = *(const float4*)(ubase + (size_t)i * 32 * H_DIM + k0);
        };
        auto store_t = [&](int b) {
            unsigned short* As = (unsigned short*)(smem + b * 36864);
            unsigned short* Gs = As + 9216;
            unsigned short* Us = As + 13824;
            #pragma unroll
            for (int i = 0; i < 4; i++) { int idx = tid + i * 512; *(ushort4*)(As + (idx >> 4) * 72 + (idx & 15) * 4) = f42bf(ra[i]); }
            #pragma unroll
            for (int i = 0; i < 2; i++) { int idx = tid + i * 512; *(ushort4*)(Gs + (idx >> 4) * 72 + (idx & 15) * 4) = f42bf(rg[i]); }
            #pragma unroll
            for (int i = 0; i < 2; i++) { int idx = tid + i * 512; *(ushort4*)(Us + (idx >> 4) * 72 + (idx & 15) * 4) = f42bf(ru[i]); }
        };
        auto mm = [&](int b) {
            const unsigned short* As = (const unsigned short*)(smem + b * 36864);
            const unsigned short* Bs = As + 9216 + wn * 4608;   // gate or up rows
            #pragma unroll
            for (int kk = 0; kk < 2; kk++) {
                bf16x8_t af[2], bfr[4];
                #pragma unroll
                for (int q = 0; q < 2; q++)
                    af[q] = *(const bf16x8_t*)(As + (wm * 32 + q * 16 + lrow) * 72 + kk * 32 + quad * 8);
                #pragma unroll
                for (int q = 0; q < 4; q++)
                    bfr[q] = *(const bf16x8_t*)(Bs + (q * 16 + lrow) * 72 + kk * 32 + quad * 8);
                #pragma unroll
                for (int a = 0; a < 2; a++)
                    #pragma unroll
                    for (int c = 0; c < 4; c++)
                        acc[a][c] = __builtin_amdgcn_mfma_f32_16x16x32_bf16(af[a], bfr[c], acc[a][c], 0, 0, 0);
            }
        };

        load_t(0);
        store_t(0);
        __syncthreads();
        for (int k = 0; k < 32; k++) {
            if (k < 31) load_t((k + 1) * 64);   // prefetch next tile into regs
            mm(k & 1);                          // MFMA on current buffer (lgkm only)
            if (k < 31) store_t((k + 1) & 1);   // vmcnt wait lands here
            __syncthreads();
        }

        // epilogue: gate waves -> GL (overlay buf0), up waves combine -> hbuf
        float* GL = (float*)smem;               // [128][68] fp32 = 34816 B < 36864
        if (wn == 0) {
            #pragma unroll
            for (int a = 0; a < 2; a++)
                #pragma unroll
                for (int c = 0; c < 4; c++)
                    #pragma unroll
                    for (int r = 0; r < 4; r++) {
                        int row = wm * 32 + a * 16 + quad * 4 + r;
                        GL[row * 68 + c * 16 + lrow] = acc[a][c][r];
                    }
        }
        __syncthreads();
        if (wn == 1) {
            #pragma unroll
            for (int a = 0; a < 2; a++)
                #pragma unroll
                for (int r = 0; r < 4; r++) {
                    int row = wm * 32 + a * 16 + quad * 4 + r;
                    int m = m0 + row;
                    if (m < cnt) {
                        int ent = etok[e * T_TOK + m];
                        float w = ew[e * T_TOK + m];
                        #pragma unroll
                        for (int c = 0; c < 4; c++) {
                            int colI = c * 16 + lrow;
                            float g = GL[row * 68 + colI];
                            float u = acc[a][c][r];
                            float hv = g / (1.f + __expf(-g)) * u * w;
                            hbuf[(size_t)ent * I_DIM + i0 + colI] = f2bf(hv);
                        }
                    }
                }
        }
        __syncthreads();   // protect GL/buf0 before next m0 pass restages
    }
}

// ---------------- Down grouped GEMM: out[tok] += h @ Wd^T (scatter atomicAdd) ----------------
// grid (16 H-tiles of 128, 32 experts) = 512 blocks, 512 thr, M=128, N=128, BK=64
__global__ __launch_bounds__(512, 4) void moe_down(
    const unsigned short* __restrict__ hbuf,  // [2T, I] bf16
    const float* __restrict__ dw,             // [E, H, I]
    const int* __restrict__ counts,
    const int* __restrict__ etok,
    float* __restrict__ out)                  // [T, H] fp32, pre-zeroed
{
    // per buffer (36864 B): A[128][72] bf16 (18432) | D[128][72] (18432)
    __shared__ __align__(16) unsigned char smem[73728];
    const int e   = blockIdx.y;
    const int n0  = blockIdx.x * 128;
    const int cnt = counts[e];
    const int tid = threadIdx.x;
    const int wid = tid >> 6, lane = tid & 63;
    const int wm = wid >> 1, wn = wid & 1;      // 4 M-waves x 2 N-waves
    const int lrow = lane & 15, quad = lane >> 4;

    const float* dbase = dw + ((size_t)e * H_DIM + n0 + (tid >> 4)) * I_DIM + (tid & 15) * 4;

    for (int m0 = 0; m0 < cnt; m0 += 128) {
        const unsigned short* arow[2];
        #pragma unroll
        for (int i = 0; i < 2; i++) {
            int idx = tid + i * 512;            // 1024 chunks of 8 bf16
            int m = m0 + (idx >> 3);
            int ent = (m < cnt) ? etok[e * T_TOK + m] : 0;
            arow[i] = hbuf + (size_t)ent * I_DIM + (idx & 7) * 8;
        }

        f32x4_t acc[2][4];
        #pragma unroll
        for (int a = 0; a < 2; a++)
            #pragma unroll
            for (int c = 0; c < 4; c++) acc[a][c] = (f32x4_t){0.f, 0.f, 0.f, 0.f};

        uint4 raa[2]; float4 rd[4];
        auto load_t = [&](int k0) {
            #pragma unroll
            for (int i = 0; i < 2; i++) raa[i] = *(const uint4*)(arow[i] + k0);
            #pragma unroll
            for (int i = 0; i < 4; i++) rd[i] = *(const float4*)(dbase + (size_t)i * 32 * I_DIM + k0);
        };
        auto store_t = [&](int b) {
            unsigned short* As = (unsigned short*)(smem + b * 36864);
            unsigned short* Ds = As + 9216;
            #pragma unroll
            for (int i = 0; i < 2; i++) { int idx = tid + i * 512; *(uint4*)(As + (idx >> 3) * 72 + (idx & 7) * 8) = raa[i]; }
            #pragma unroll
            for (int i = 0; i < 4; i++) { int idx = tid + i * 512; *(ushort4*)(Ds + (idx >> 4) * 72 + (idx & 15) * 4) = f42bf(rd[i]); }
        };
        auto mm = [&](int b) {
            const unsigned short* As = (const unsigned short*)(smem + b * 36864);
            const unsigned short* Ds = As + 9216;
            #pragma unroll
            for (int kk = 0; kk < 2; kk++) {
                bf16x8_t af[2], bfr[4];
                #pragma unroll
                for (int q = 0; q < 2; q++)
                    af[q] = *(const bf16x8_t*)(As + (wm * 32 + q * 16 + lrow) * 72 + kk * 32 + quad * 8);
                #pragma unroll
                for (int q = 0; q < 4; q++)
                    bfr[q] = *(const bf16x8_t*)(Ds + (wn * 64 + q * 16 + lrow) * 72 + kk * 32 + quad * 8);
                #pragma unroll
                for (int a = 0; a < 2; a++)
                    #pragma unroll
                    for (int c = 0; c < 4; c++)
                        acc[a][c] = __builtin_amdgcn_mfma_f32_16x16x32_bf16(af[a], bfr[c], acc[a][c], 0, 0, 0);
            }
        };

        load_t(0);
        store_t(0);
        __syncthreads();
        for (int k = 0; k < 16; k++) {
            if (k < 15) load_t((k + 1) * 64);
            mm(k & 1);
            if (k < 15) store_t((k + 1) & 1);
            __syncthreads();
        }

        #pragma unroll
        for (int a = 0; a < 2; a++)
            #pragma unroll
            for (int r = 0; r < 4; r++) {
                int row = wm * 32 + a * 16 + quad * 4 + r;
                int m = m0 + row;
                if (m < cnt) {
                    int tok = etok[e * T_TOK + m] >> 1;
                    float* orow = out + (size_t)tok * H_DIM + n0 + wn * 64;
                    #pragma unroll
                    for (int c = 0; c < 4; c++)
                        atomicAdd(orow + c * 16 + lrow, acc[a][c][r]);
                }
            }
    }
}

extern "C" void kernel_launch(void* const* d_in, const int* in_sizes, int n_in,
                              void* d_out, int out_size, void* d_ws, size_t ws_size,
                              hipStream_t stream) {
    const float* x   = (const float*)d_in[0];   // [T, H]
    const float* gwr = (const float*)d_in[1];   // [E, H] router
    const float* gw  = (const float*)d_in[2];   // [E, I, H]
    const float* uw  = (const float*)d_in[3];   // [E, I, H]
    const float* dw  = (const float*)d_in[4];   // [E, H, I]
    float* out = (float*)d_out;

    char* ws = (char*)d_ws;
    int*   counts = (int*)ws;                                // 32 ints
    int*   etok   = (int*)(ws + 4096);                       // [E*T] (token<<1 | slot)
    float* ew     = (float*)(ws + 4096 + 131072);            // [E*T]
    unsigned short* hbuf = (unsigned short*)(ws + 4096 + 262144);  // [2T, I] bf16 = 4 MB

    hipMemsetAsync(counts, 0, 128, stream);
    hipMemsetAsync(d_out, 0, (size_t)out_size * sizeof(float), stream);

    moe_router<<<T_TOK, 256, 0, stream>>>(x, gwr, counts, etok, ew);
    moe_gateup<<<dim3(I_DIM / 64, NE), 512, 0, stream>>>(x, gw, uw, counts, etok, ew, hbuf);
    moe_down<<<dim3(H_DIM / 128, NE), 512, 0, stream>>>(hbuf, dw, counts, etok, out);
}